// Round 2
// baseline (287.894 us; speedup 1.0000x reference)
//
#include <hip/hip_runtime.h>

#define N 20000
#define E 200000
#define IN 128
#define OUT 128
#define NB 8
#define SI 16
#define SO 16
#define R 230
#define T 365

// Scratch in module .bss. d_ws untouched; kernel_launch makes no runtime API
// calls (kernel launches only) — graph-capture safe.
__device__ float g_W_t[(size_t)R * NB * SO * SI];  // W transposed: [r][b][ol][i]
__device__ float g_agg[(size_t)N * OUT];           // agg * node_norm, plain stores
__device__ int   g_cnt[N];
__device__ int   g_off[N];
__device__ int   g_cur[N];
__device__ int   g_eid[E];
__device__ int   g_total;

// Transpose W into [r][b][ol][i] (contiguous i -> float4 loads in agg) and
// zero the histogram + bump counter.
__global__ void prep_kernel(const float* __restrict__ weight) {
    int t = blockIdx.x * blockDim.x + threadIdx.x;
    if (t < R * NB * SO * SI) {
        int r  = t >> 11;
        int b  = (t >> 8) & 7;
        int ol = (t >> 4) & 15;
        int i  = t & 15;
        g_W_t[t] = weight[(long)r * 2048 + b * 256 + i * 16 + ol];
    }
    if (t < N) g_cnt[t] = 0;
    if (t == 0) g_total = 0;
}

__global__ void hist_kernel(const int* __restrict__ edge_dst) {
    int e = blockIdx.x * blockDim.x + threadIdx.x;
    if (e < E) atomicAdd(&g_cnt[edge_dst[e]], 1);
}

// Bump-allocator row offsets: contiguity per node is all we need; row order
// across nodes is irrelevant. Replaces the single-block scan.
__global__ void alloc_kernel() {
    int n = blockIdx.x * blockDim.x + threadIdx.x;
    if (n < N) {
        int c = g_cnt[n];
        int off = atomicAdd(&g_total, c);
        g_off[n] = off;
        g_cur[n] = off;
    }
}

__global__ void scatter_kernel(const int* __restrict__ edge_dst) {
    int e = blockIdx.x * blockDim.x + threadIdx.x;
    if (e < E) {
        int pos = atomicAdd(&g_cur[edge_dst[e]], 1);
        g_eid[pos] = e;
    }
}

// One block = one destination node. 256 threads = 2 edge-slots x 128 features.
// Each slot processes alternating edges of the node with a 1-ahead metadata
// pipeline; W read as 4x float4 from the transposed layout. Plain store of
// agg * node_norm (no atomics anywhere on the float path).
__global__ __launch_bounds__(256) void agg_kernel(
        const float* __restrict__ h,
        const float* __restrict__ edge_norm,
        const float* __restrict__ node_norm,
        const int* __restrict__ edge_src,
        const int* __restrict__ edge_type) {
    __shared__ float part[128];
    const int n    = blockIdx.x;
    const int tid  = threadIdx.x;
    const int slot = tid >> 7;      // 0,1
    const int o    = tid & 127;
    const int b    = o >> 4;
    const int ol   = o & 15;

    const int st  = g_off[n];
    const int cnt = g_cnt[n];

    float agg = 0.f;
    int k = slot;
    if (k < cnt) {
        int e0 = g_eid[st + k];
        int   s  = edge_src[e0];
        int   r  = edge_type[e0];
        float en = edge_norm[e0];
        while (k < cnt) {
            int k2 = k + 2;
            int s2 = 0, r2 = 0;
            float en2 = 0.f;
            if (k2 < cnt) {
                int e2 = g_eid[st + k2];
                s2  = edge_src[e2];
                r2  = edge_type[e2];
                en2 = edge_norm[e2];
            }
            const float4* hp =
                reinterpret_cast<const float4*>(h + (long)s * IN + b * SI);
            const float4* wp = reinterpret_cast<const float4*>(
                g_W_t + (long)r * 2048 + b * 256 + ol * 16);
            float4 h0 = hp[0], h1 = hp[1], h2 = hp[2], h3 = hp[3];
            float4 w0 = wp[0], w1 = wp[1], w2 = wp[2], w3 = wp[3];
            float m0 = 0.f, m1 = 0.f;
            m0 = fmaf(h0.x, w0.x, m0); m0 = fmaf(h0.y, w0.y, m0);
            m0 = fmaf(h0.z, w0.z, m0); m0 = fmaf(h0.w, w0.w, m0);
            m1 = fmaf(h1.x, w1.x, m1); m1 = fmaf(h1.y, w1.y, m1);
            m1 = fmaf(h1.z, w1.z, m1); m1 = fmaf(h1.w, w1.w, m1);
            m0 = fmaf(h2.x, w2.x, m0); m0 = fmaf(h2.y, w2.y, m0);
            m0 = fmaf(h2.z, w2.z, m0); m0 = fmaf(h2.w, w2.w, m0);
            m1 = fmaf(h3.x, w3.x, m1); m1 = fmaf(h3.y, w3.y, m1);
            m1 = fmaf(h3.z, w3.z, m1); m1 = fmaf(h3.w, w3.w, m1);
            agg = fmaf(en, m0 + m1, agg);
            s = s2; r = r2; en = en2; k = k2;
        }
    }
    if (slot == 1) part[o] = agg;
    __syncthreads();
    if (slot == 0) {
        float a = agg + part[o];
        g_agg[(long)n * OUT + o] = a * node_norm[n];
    }
}

// Self-loop GEMM + epilogue + time-embedding gather.
// 32 nodes/block, 256 threads = 2 node-halves x 128 out-features.
// h tile in LDS, i-major padded to stride 36 floats (16B-aligned float4
// broadcasts, banks spread); loop_weight streamed coalesced (L2-warm).
__global__ __launch_bounds__(256) void node_kernel(
        const float* __restrict__ h,
        const float* __restrict__ h_bias,
        const float* __restrict__ loop_weight,
        const float* __restrict__ time_embed,
        const int* __restrict__ time_idx,
        float* __restrict__ out) {
    __shared__ float hsm[IN * 36];       // hsm[i*36 + nl], nl in [0,32)
    const int tid  = threadIdx.x;
    const int half = tid >> 7;           // 0,1
    const int o    = tid & 127;
    const int base = blockIdx.x * 32;

    for (int k = tid; k < 32 * IN; k += 256) {
        int nl = k >> 7;
        int i  = k & 127;
        hsm[i * 36 + nl] = h[(long)(base + nl) * IN + i];
    }
    __syncthreads();

    float acc[16];
#pragma unroll
    for (int q = 0; q < 16; ++q) acc[q] = 0.f;

#pragma unroll 4
    for (int i = 0; i < IN; ++i) {
        float w = loop_weight[(long)i * OUT + o];
        const float* row = &hsm[i * 36 + half * 16];
        float4 a0 = *reinterpret_cast<const float4*>(row + 0);
        float4 a1 = *reinterpret_cast<const float4*>(row + 4);
        float4 a2 = *reinterpret_cast<const float4*>(row + 8);
        float4 a3 = *reinterpret_cast<const float4*>(row + 12);
        acc[0]  = fmaf(a0.x, w, acc[0]);  acc[1]  = fmaf(a0.y, w, acc[1]);
        acc[2]  = fmaf(a0.z, w, acc[2]);  acc[3]  = fmaf(a0.w, w, acc[3]);
        acc[4]  = fmaf(a1.x, w, acc[4]);  acc[5]  = fmaf(a1.y, w, acc[5]);
        acc[6]  = fmaf(a1.z, w, acc[6]);  acc[7]  = fmaf(a1.w, w, acc[7]);
        acc[8]  = fmaf(a2.x, w, acc[8]);  acc[9]  = fmaf(a2.y, w, acc[9]);
        acc[10] = fmaf(a2.z, w, acc[10]); acc[11] = fmaf(a2.w, w, acc[11]);
        acc[12] = fmaf(a3.x, w, acc[12]); acc[13] = fmaf(a3.y, w, acc[13]);
        acc[14] = fmaf(a3.z, w, acc[14]); acc[15] = fmaf(a3.w, w, acc[15]);
    }

    const float bias = h_bias[o];
#pragma unroll
    for (int q = 0; q < 16; ++q) {
        int n = base + half * 16 + q;
        float v = g_agg[(long)n * OUT + o] + bias + acc[q];
        out[(long)n * OUT + o] = fmaxf(v, 0.f);
        out[(long)N * OUT + (long)n * IN + o] =
            time_embed[(long)time_idx[n] * IN + o];
    }
}

extern "C" void kernel_launch(void* const* d_in, const int* in_sizes, int n_in,
                              void* d_out, int out_size, void* d_ws, size_t ws_size,
                              hipStream_t stream) {
    const float* h           = (const float*)d_in[0];
    const float* edge_norm   = (const float*)d_in[1];
    const float* node_norm   = (const float*)d_in[2];
    const float* weight      = (const float*)d_in[3];
    const float* h_bias      = (const float*)d_in[4];
    const float* loop_weight = (const float*)d_in[5];
    const float* time_embed  = (const float*)d_in[6];
    const int*   edge_src    = (const int*)d_in[7];
    const int*   edge_dst    = (const int*)d_in[8];
    const int*   edge_type   = (const int*)d_in[9];
    const int*   time_idx    = (const int*)d_in[10];
    float* out = (float*)d_out;

    prep_kernel<<<(R * NB * SO * SI + 255) / 256, 256, 0, stream>>>(weight);
    hist_kernel<<<(E + 255) / 256, 256, 0, stream>>>(edge_dst);
    alloc_kernel<<<(N + 255) / 256, 256, 0, stream>>>();
    scatter_kernel<<<(E + 255) / 256, 256, 0, stream>>>(edge_dst);
    agg_kernel<<<N, 256, 0, stream>>>(h, edge_norm, node_norm,
                                      edge_src, edge_type);
    node_kernel<<<N / 32, 256, 0, stream>>>(h, h_bias, loop_weight,
                                            time_embed, time_idx, out);
}